// Round 6
// baseline (1170.177 us; speedup 1.0000x reference)
//
#include <hip/hip_runtime.h>
#include <hip/hip_bf16.h>

typedef __attribute__((ext_vector_type(8))) short s8b;     // 8 bf16 (4 VGPRs)
typedef __attribute__((ext_vector_type(4))) float f32x4;   // MFMA accumulator
typedef __attribute__((ext_vector_type(4))) unsigned u32x4;

#define NND 50000
#define NED 800000
#define EPB 128     // edges per block
#define EPW 32      // edges per wave

// workspace layout (bf16-element offsets for weights, byte offsets for f32)
#define WM1T_OFF 0         // [128][384] folded+transposed Wm1'
#define WM2T_OFF 49152     // [128][128]
#define WV1T_OFF 65536     // [128][128]
#define WV2T_OFF 81920     // [80][128]
#define WS1T_OFF 92160     // [128][256]
#define WS2T_OFF 124928    // [128][128]
#define BM1F_BYTE 282624   // 128 f32 (folded bias)
#define ACC_BYTE  283136   // f32 accumulators start (16B aligned)
#define ZACC_ELEMS (NND*48)
#define MACC_ELEMS (NND*128)
#define ACC_TOTAL (ZACC_ELEMS + MACC_ELEMS + NND)
#define WS_NEED (ACC_BYTE + (size_t)ACC_TOTAL*4)

// accurate RNE cvt (weight prep only)
__device__ __forceinline__ short f2bs(float x){
    __hip_bfloat16 b = __float2bfloat16(x);
    return __builtin_bit_cast(short, b);
}
// fast cvt: round-half-up, 2 VALU ops (finite inputs only)
__device__ __forceinline__ short f2bs_fast(float x){
    unsigned u = __builtin_bit_cast(unsigned, x) + 0x8000u;
    return (short)(u >> 16);
}
// pack 2 floats -> 2 bf16 in one dword (lo=a, hi=b): add,add,v_perm = 3 ops
__device__ __forceinline__ unsigned pk2(float a, float b){
    unsigned ua = __builtin_bit_cast(unsigned, a) + 0x8000u;
    unsigned ub = __builtin_bit_cast(unsigned, b) + 0x8000u;
    return __builtin_amdgcn_perm(ub, ua, 0x07060302u);
}
__device__ __forceinline__ float bs2f(short s){
    unsigned u = ((unsigned)(unsigned short)s) << 16;
    return __builtin_bit_cast(float, u);
}
__device__ __forceinline__ float upk_lo(unsigned u){   // p=0 element
    return __builtin_bit_cast(float, u << 16);
}
__device__ __forceinline__ float upk_hi(unsigned u){   // p=1 element
    return __builtin_bit_cast(float, u & 0xffff0000u);
}
// silu via hardware rcp (1 ulp) — avoids the IEEE div expansion
__device__ __forceinline__ float silu_f(float x){
    float e = __expf(-x);
    return x * __builtin_amdgcn_rcpf(1.0f + e);
}

// load 8 consecutive f32 (16B-aligned) -> bf16 A/B fragment (12 VALU ops)
__device__ __forceinline__ s8b load8f_bf(const float* p){
    f32x4 a = *(const f32x4*)p;
    f32x4 b = *(const f32x4*)(p + 4);
    u32x4 r;
    r[0] = pk2(a[0], a[1]); r[1] = pk2(a[2], a[3]);
    r[2] = pk2(b[0], b[1]); r[3] = pk2(b[2], b[3]);
    return __builtin_bit_cast(s8b, r);
}

#define MFMA16(a,b,c) __builtin_amdgcn_mfma_f32_16x16x32_bf16((a),(b),(c),0,0,0)
// LDS-only ordering: do NOT drain vmcnt (atomics must free-run)
#define LDS_FENCE() asm volatile("s_waitcnt lgkmcnt(0)" ::: "memory")

// ---------------- zero accumulators (no SDMA memset — coherence with atomics) ----------------
__global__ __launch_bounds__(256) void zero_kernel(float* __restrict__ p, int n)
{
    int i = blockIdx.x*256 + threadIdx.x;
    int stride = gridDim.x*256;
    for (; i < n; i += stride) p[i] = 0.0f;
}

// ---------------- weight prep ----------------
__global__ __launch_bounds__(256) void fold_kernel(
    const float* __restrict__ We, const float* __restrict__ be,
    const float* __restrict__ Wm1, const float* __restrict__ bm1,
    short* __restrict__ Wm1T, float* __restrict__ bm1f)
{
    int idx = blockIdx.x*256 + threadIdx.x;
    if (idx >= 128*384) return;
    int n = idx / 384, k = idx - n*384;
    float v;
    if (k < 356) v = Wm1[(size_t)k*128 + n];
    else if (k < 372) {
        int j = k - 356; float s = 0.f;
        for (int c = 0; c < 128; c++)
            s += We[j*128 + c] * Wm1[(size_t)(356+c)*128 + n];
        v = s;
    } else v = 0.f;
    Wm1T[(size_t)n*384 + k] = f2bs(v);
    if (k == 0) {
        float s = bm1[n];
        for (int c = 0; c < 128; c++)
            s += be[c] * Wm1[(size_t)(356+c)*128 + n];
        bm1f[n] = s;
    }
}

__global__ __launch_bounds__(256) void prep_kernel(
    const float* __restrict__ Wm2, const float* __restrict__ Wv1,
    const float* __restrict__ Wv2, const float* __restrict__ Ws1,
    const float* __restrict__ Ws2, short* __restrict__ wsb)
{
    int i = blockIdx.x*256 + threadIdx.x;
    if (i < 16384) { int k=i>>7, n=i&127; wsb[WM2T_OFF + n*128 + k] = f2bs(Wm2[i]); return; }
    i -= 16384;
    if (i < 16384) { int k=i>>7, n=i&127; wsb[WV1T_OFF + n*128 + k] = f2bs(Wv1[i]); return; }
    i -= 16384;
    if (i < 10240) { int k=i/80, n=i-k*80; wsb[WV2T_OFF + n*128 + k] = f2bs(Wv2[i]); return; }
    i -= 10240;
    if (i < 32768) { int k=i>>7, n=i&127; wsb[WS1T_OFF + n*256 + k] = f2bs(Ws1[i]); return; }
    i -= 32768;
    if (i < 16384) { int k=i>>7, n=i&127; wsb[WS2T_OFF + n*128 + k] = f2bs(Ws2[i]); return; }
}

// ---------------- edge kernel ----------------
// 128 edges/block, 4 waves, each wave owns 32 edges (2 MFMA A-tiles) end-to-end.
// Z_ij lives in registers (h-parity split across the edge's 2 owner lanes);
// no zsh -> 35.8 KB LDS -> 4 blocks/CU. No __syncthreads, only lgkm fences.
__global__ __launch_bounds__(256, 4) void edge_kernel(
    const float* __restrict__ Z, const float* __restrict__ h,
    const int* __restrict__ ei,
    const float* __restrict__ edf, const float* __restrict__ edv,
    const short* __restrict__ Wm1T, const float* __restrict__ bm1f,
    const short* __restrict__ Wm2T, const float* __restrict__ bm2,
    const short* __restrict__ Wv1T, const float* __restrict__ bv1,
    const short* __restrict__ Wv2T, const float* __restrict__ bv2,
    float* __restrict__ Zacc, float* __restrict__ macc, float* __restrict__ cnt)
{
    __shared__ __align__(16) short ssh[EPB*136];  // invar/edf -> act1 -> msg -> act3 -> Z restage
    __shared__ int srcs[EPB], dsts[EPB];

    const int tid  = threadIdx.x;
    const int lane = tid & 63;
    const int wave = tid >> 6;
    const int wb   = wave * EPW;
    const int ebase= blockIdx.x * EPB;

    const int row = wb + (lane >> 1);
    const int sub = lane & 1;          // h-parity: this lane owns h = 2*sub, 2*sub+1

    // ---- Phase A1: indices + Z_ij diffs into registers (packed bf16 pairs) ----
    unsigned zp[15];    // [g=d*4+t][h-pair] for t<4 ; zp[12+d] = edv pair
    {
        const int e = ebase + row;
        const int s = ei[e], d = ei[NED + e];
        if (sub == 0) {
            srcs[row] = s; dsts[row] = d;
            atomicAdd(cnt + d, 1.0f);
        }
        const float* Zs = Z + (size_t)s*48 + sub*24;
        const float* Zd = Z + (size_t)d*48 + sub*24;
        float dv[24];
        #pragma unroll
        for (int q = 0; q < 6; q++) {
            f32x4 a = *(const f32x4*)(Zd + q*4);
            f32x4 b = *(const f32x4*)(Zs + q*4);
            dv[q*4+0] = a[0]-b[0]; dv[q*4+1] = a[1]-b[1];
            dv[q*4+2] = a[2]-b[2]; dv[q*4+3] = a[3]-b[3];
        }
        // my 6 (d,t)-groups: global groups sub*6 .. sub*6+5
        unsigned pA[6], pB[6], rc[6];
        #pragma unroll
        for (int q = 0; q < 6; q++) {
            pA[q] = pk2(dv[q*4+0], dv[q*4+1]);   // parity 0 (h=0,1)
            pB[q] = pk2(dv[q*4+2], dv[q*4+3]);   // parity 1 (h=2,3)
        }
        #pragma unroll
        for (int q = 0; q < 6; q++)
            rc[q] = (unsigned)__shfl_xor((int)(sub ? pA[q] : pB[q]), 1);
        #pragma unroll
        for (int i = 0; i < 6; i++) zp[i]   = sub ? rc[i] : pA[i];
        #pragma unroll
        for (int i = 0; i < 6; i++) zp[6+i] = sub ? pB[i] : rc[i];
        float e0 = edv[(size_t)e*3+0], e1 = edv[(size_t)e*3+1], e2 = edv[(size_t)e*3+2];
        zp[12] = pk2(e0,e0); zp[13] = pk2(e1,e1); zp[14] = pk2(e2,e2);
    }

    // ---- Phase A2: invariants (register-local Gram, h-diagonal) + edf stage ----
    {
        const int e = ebase + row;
        // unpack Z: zt[p][d][t]
        float zt0[15], zt1[15];
        #pragma unroll
        for (int i = 0; i < 15; i++) { zt0[i] = upk_lo(zp[i]); zt1[i] = upk_hi(zp[i]); }
        const int PT[15] = {0,0,0,0,0,1,1,1,1,2,2,2,3,3,4};
        const int PR[15] = {0,1,2,3,4,1,2,3,4,2,3,4,3,4,4};
        float v0[15], v1[15];
        float ssql = 0.f;
        #pragma unroll
        for (int k = 0; k < 15; k++) {
            const int tt = PT[k], rr = PR[k];
            float a0 = 0.f, a1 = 0.f;
            #pragma unroll
            for (int d2 = 0; d2 < 3; d2++) {
                const int gt = (tt < 4) ? d2*4 + tt : 12 + d2;
                const int gr = (rr < 4) ? d2*4 + rr : 12 + d2;
                a0 += zt0[gt]*zt0[gr];
                a1 += zt1[gt]*zt1[gr];
            }
            v0[k] = a0; v1[k] = a1;
            const float w = (tt == rr) ? 1.0f : 2.0f;
            ssql += w*(a0*a0 + a1*a1);
        }
        float ssq = ssql + __shfl_xor(ssql, 1);
        const float rn = __builtin_amdgcn_rsqf(fmaxf(ssq, 1e-24f));
        #pragma unroll
        for (int k = 0; k < 15; k++) {
            const int tt = PT[k], rr = PR[k];
            unsigned pkv = pk2(v0[k]*rn, v1[k]*rn);
            *(unsigned*)(&ssh[row*136 + tt*20 + rr*4 + 2*sub]) = pkv;
            if (tt != rr)
                *(unsigned*)(&ssh[row*136 + rr*20 + tt*4 + 2*sub]) = pkv;
        }
        // edf: 16 values, 8 per sub-lane, packed b32 writes
        {
            const float* ep = edf + (size_t)e*16 + sub*8;
            f32x4 f0 = *(const f32x4*)ep, f1 = *(const f32x4*)(ep+4);
            int cb = row*136 + 100 + sub*8;
            *(unsigned*)(&ssh[cb+0]) = pk2(f0[0], f0[1]);
            *(unsigned*)(&ssh[cb+2]) = pk2(f0[2], f0[3]);
            *(unsigned*)(&ssh[cb+4]) = pk2(f1[0], f1[1]);
            *(unsigned*)(&ssh[cb+6]) = pk2(f1[2], f1[3]);
        }
        #pragma unroll
        for (int k = 0; k < 5; k++)
            *(unsigned*)(&ssh[row*136 + 116 + (sub*5 + k)*2]) = 0;
    }
    LDS_FENCE();

    // ---- GEMM phase: 2 A-tiles (32 edges) share every B-fragment load ----
    const int quad = lane >> 4;
    const int c15  = lane & 15;
    const int rA0  = wb + c15;
    const int rA1  = wb + 16 + c15;
    const float* hd0 = h + (size_t)dsts[rA0]*128 + quad*8;
    const float* hs0 = h + (size_t)srcs[rA0]*128 + quad*8;
    const float* hd1 = h + (size_t)dsts[rA1]*128 + quad*8;
    const float* hs1 = h + (size_t)srcs[rA1]*128 + quad*8;
    const short* sA0 = ssh + rA0*136 + quad*8;
    const short* sA1 = ssh + rA1*136 + quad*8;
    const f32x4 z4 = {0.f,0.f,0.f,0.f};

    // Layer 1: x'[384] @ Wm1T' -> 128
    f32x4 acc1[2][8];
    #pragma unroll
    for (int nt = 0; nt < 8; nt++) { acc1[0][nt] = z4; acc1[1][nt] = z4; }
    {
        const short* Bp = Wm1T + (size_t)c15*384 + quad*8;
        #pragma unroll
        for (int ks = 0; ks < 12; ks++) {
            s8b a0, a1;
            if (ks < 4)      { a0 = load8f_bf(hd0 + ks*32);     a1 = load8f_bf(hd1 + ks*32); }
            else if (ks < 8) { a0 = load8f_bf(hs0 + (ks-4)*32); a1 = load8f_bf(hs1 + (ks-4)*32); }
            else             { a0 = *(const s8b*)(sA0 + (ks-8)*32); a1 = *(const s8b*)(sA1 + (ks-8)*32); }
            #pragma unroll
            for (int nt = 0; nt < 8; nt++) {
                s8b b = *(const s8b*)(Bp + nt*(16*384) + ks*32);
                acc1[0][nt] = MFMA16(a0, b, acc1[0][nt]);
                acc1[1][nt] = MFMA16(a1, b, acc1[1][nt]);
            }
        }
    }
    LDS_FENCE();
    #pragma unroll
    for (int nt = 0; nt < 8; nt++) {
        const int col = nt*16 + c15;
        const float bias = bm1f[col];
        #pragma unroll
        for (int tl = 0; tl < 2; tl++)
            #pragma unroll
            for (int r = 0; r < 4; r++)
                ssh[(wb + tl*16 + quad*4 + r)*136 + col] = f2bs_fast(silu_f(acc1[tl][nt][r] + bias));
    }
    LDS_FENCE();

    // Layer 2: act1 @ Wm2 -> msg ; atomic-add msg (f32) to macc
    f32x4 acc2[2][8];
    #pragma unroll
    for (int nt = 0; nt < 8; nt++) { acc2[0][nt] = z4; acc2[1][nt] = z4; }
    {
        const short* Bp = Wm2T + (size_t)c15*128 + quad*8;
        #pragma unroll
        for (int ks = 0; ks < 4; ks++) {
            s8b a0 = *(const s8b*)(sA0 + ks*32);
            s8b a1 = *(const s8b*)(sA1 + ks*32);
            #pragma unroll
            for (int nt = 0; nt < 8; nt++) {
                s8b b = *(const s8b*)(Bp + nt*(16*128) + ks*32);
                acc2[0][nt] = MFMA16(a0, b, acc2[0][nt]);
                acc2[1][nt] = MFMA16(a1, b, acc2[1][nt]);
            }
        }
    }
    LDS_FENCE();
    #pragma unroll
    for (int nt = 0; nt < 8; nt++) {
        const int col = nt*16 + c15;
        const float bias = bm2[col];
        #pragma unroll
        for (int tl = 0; tl < 2; tl++)
            #pragma unroll
            for (int r = 0; r < 4; r++) {
                const int rw = wb + tl*16 + quad*4 + r;
                float v = silu_f(acc2[tl][nt][r] + bias);
                atomicAdd(macc + (size_t)dsts[rw]*128 + col, v);
                ssh[rw*136 + col] = f2bs_fast(v);
            }
    }
    LDS_FENCE();

    // Layer 3: msg @ Wv1 -> act3
    f32x4 acc3[2][8];
    #pragma unroll
    for (int nt = 0; nt < 8; nt++) { acc3[0][nt] = z4; acc3[1][nt] = z4; }
    {
        const short* Bp = Wv1T + (size_t)c15*128 + quad*8;
        #pragma unroll
        for (int ks = 0; ks < 4; ks++) {
            s8b a0 = *(const s8b*)(sA0 + ks*32);
            s8b a1 = *(const s8b*)(sA1 + ks*32);
            #pragma unroll
            for (int nt = 0; nt < 8; nt++) {
                s8b b = *(const s8b*)(Bp + nt*(16*128) + ks*32);
                acc3[0][nt] = MFMA16(a0, b, acc3[0][nt]);
                acc3[1][nt] = MFMA16(a1, b, acc3[1][nt]);
            }
        }
    }
    LDS_FENCE();
    #pragma unroll
    for (int nt = 0; nt < 8; nt++) {
        const int col = nt*16 + c15;
        const float bias = bv1[col];
        #pragma unroll
        for (int tl = 0; tl < 2; tl++)
            #pragma unroll
            for (int r = 0; r < 4; r++)
                ssh[(wb + tl*16 + quad*4 + r)*136 + col] = f2bs_fast(silu_f(acc3[tl][nt][r] + bias));
    }
    LDS_FENCE();

    // Layer 4: act3 @ Wv2 -> basis[80]
    f32x4 acc4[2][5];
    #pragma unroll
    for (int nt = 0; nt < 5; nt++) { acc4[0][nt] = z4; acc4[1][nt] = z4; }
    {
        const short* Bp = Wv2T + (size_t)c15*128 + quad*8;
        #pragma unroll
        for (int ks = 0; ks < 4; ks++) {
            s8b a0 = *(const s8b*)(sA0 + ks*32);
            s8b a1 = *(const s8b*)(sA1 + ks*32);
            #pragma unroll
            for (int nt = 0; nt < 5; nt++) {
                s8b b = *(const s8b*)(Bp + nt*(16*128) + ks*32);
                acc4[0][nt] = MFMA16(a0, b, acc4[0][nt]);
                acc4[1][nt] = MFMA16(a1, b, acc4[1][nt]);
            }
        }
    }
    // act3 is dead now -> restage Z_ij from registers into ssh (cols 0..59)
    LDS_FENCE();   // ensure L4 A-fragment ds_reads retired before overwrite
    {
        #pragma unroll
        for (int d2 = 0; d2 < 3; d2++) {
            #pragma unroll
            for (int t = 0; t < 4; t++)
                *(unsigned*)(&ssh[row*136 + d2*20 + t*4 + 2*sub]) = zp[d2*4 + t];
            *(unsigned*)(&ssh[row*136 + d2*20 + 16 + 2*sub]) = zp[12 + d2];
        }
    }
    LDS_FENCE();
    // contract with Z_ij ; atomic to Zacc
    {
        const int hh = c15 & 3;                   // basis col = t*16 + (k*4+h); c15 = k*4+h
        float bs[5];
        #pragma unroll
        for (int t = 0; t < 5; t++) bs[t] = bv2[t*16 + c15];
        #pragma unroll
        for (int tl = 0; tl < 2; tl++)
            #pragma unroll
            for (int r = 0; r < 4; r++) {
                const int rw = wb + tl*16 + quad*4 + r;
                const int eg = dsts[rw];
                float bt[5];
                #pragma unroll
                for (int t = 0; t < 5; t++) bt[t] = acc4[tl][t][r] + bs[t];
                #pragma unroll
                for (int dd = 0; dd < 3; dd++) {
                    float s0 = 0.f;
                    #pragma unroll
                    for (int t = 0; t < 5; t++)
                        s0 += bs2f(ssh[rw*136 + dd*20 + t*4 + hh]) * bt[t];
                    atomicAdd(Zacc + (size_t)eg*48 + dd*16 + c15, s0);
                }
            }
    }
}

// ---------------- node kernel ----------------
__global__ __launch_bounds__(256) void node_kernel(
    const float* __restrict__ h,
    const short* __restrict__ Ws1T, const float* __restrict__ bs1,
    const short* __restrict__ Ws2T, const float* __restrict__ bs2,
    const float* __restrict__ Zacc, const float* __restrict__ macc,
    const float* __restrict__ cnt, float* __restrict__ out)
{
    __shared__ __align__(16) short ssh[64*136];   // m stage -> act1
    const int tid = threadIdx.x, lane = tid & 63, wave = tid >> 6;
    const int mb = wave*16;
    const int nbase = blockIdx.x * 64;

    // Z_out = Zacc / max(cnt,1)
    for (int i = tid; i < 64*48; i += 256) {
        int nl = i / 48, c2 = i - nl*48;
        int nd = nbase + nl;
        if (nd < NND) {
            float ct = fmaxf(cnt[nd], 1.0f);
            out[(size_t)nd*48 + c2] = Zacc[(size_t)nd*48 + c2] / ct;
        }
    }

    // stage m (bf16), wave-private rows
    {
        const int row = mb + (lane >> 2);
        const int sub = lane & 3;
        int nd = nbase + row; if (nd >= NND) nd = 0;
        const float* mr = macc + (size_t)nd*128 + sub*32;
        #pragma unroll
        for (int j = 0; j < 8; j++) {
            f32x4 v = *(const f32x4*)(mr + j*4);
            int cb = row*136 + sub*32 + j*4;
            *(unsigned*)(&ssh[cb+0]) = pk2(v[0], v[1]);
            *(unsigned*)(&ssh[cb+2]) = pk2(v[2], v[3]);
        }
    }
    LDS_FENCE();

    const int quad = lane >> 4, c15 = lane & 15;
    const int rA = mb + c15;
    int ndA = nbase + rA; if (ndA >= NND) ndA = 0;   // clamp; stores guarded
    const float* hA = h + (size_t)ndA*128 + quad*8;
    const short* sA = ssh + rA*136 + quad*8;
    const f32x4 z4 = {0.f,0.f,0.f,0.f};

    // GEMM1: [h | m] (K=256) @ Ws1
    f32x4 acc1[8];
    #pragma unroll
    for (int nt = 0; nt < 8; nt++) acc1[nt] = z4;
    {
        const short* Bp = Ws1T + (size_t)c15*256 + quad*8;
        #pragma unroll
        for (int ks = 0; ks < 8; ks++) {
            s8b a;
            if (ks < 4) a = load8f_bf(hA + ks*32);
            else        a = *(const s8b*)(sA + (ks-4)*32);
            #pragma unroll
            for (int nt = 0; nt < 8; nt++) {
                s8b b = *(const s8b*)(Bp + nt*(16*256) + ks*32);
                acc1[nt] = MFMA16(a, b, acc1[nt]);
            }
        }
    }
    LDS_FENCE();
    #pragma unroll
    for (int nt = 0; nt < 8; nt++) {
        const int col = nt*16 + c15;
        const float bias = bs1[col];
        #pragma unroll
        for (int r = 0; r < 4; r++)
            ssh[(mb + quad*4 + r)*136 + col] = f2bs_fast(silu_f(acc1[nt][r] + bias));
    }
    LDS_FENCE();

    // GEMM2: act @ Ws2 -> h_out
    f32x4 acc2[8];
    #pragma unroll
    for (int nt = 0; nt < 8; nt++) acc2[nt] = z4;
    {
        const short* Bp = Ws2T + (size_t)c15*128 + quad*8;
        #pragma unroll
        for (int ks = 0; ks < 4; ks++) {
            s8b a = *(const s8b*)(sA + ks*32);
            #pragma unroll
            for (int nt = 0; nt < 8; nt++) {
                s8b b = *(const s8b*)(Bp + nt*(16*128) + ks*32);
                acc2[nt] = MFMA16(a, b, acc2[nt]);
            }
        }
    }
    {
        float* oh = out + (size_t)NND*48;
        #pragma unroll
        for (int nt = 0; nt < 8; nt++) {
            const int col = nt*16 + c15;
            const float bias = bs2[col];
            #pragma unroll
            for (int r = 0; r < 4; r++) {
                const int rw = mb + quad*4 + r;
                const int nd = nbase + rw;
                if (nd < NND)
                    oh[(size_t)nd*128 + col] = acc2[nt][r] + bias;
            }
        }
    }
}

extern "C" void kernel_launch(void* const* d_in, const int* in_sizes, int n_in,
                              void* d_out, int out_size, void* d_ws, size_t ws_size,
                              hipStream_t stream)
{
    const float* Z   = (const float*)d_in[0];
    const float* h   = (const float*)d_in[1];
    const int*   ei  = (const int*)d_in[2];
    const float* edf = (const float*)d_in[3];
    const float* edv = (const float*)d_in[4];
    // d_in[5] = edge_distance (unused by reference)
    const float* We  = (const float*)d_in[6];
    const float* be  = (const float*)d_in[7];
    const float* Wm1 = (const float*)d_in[8];
    const float* bm1 = (const float*)d_in[9];
    const float* Wm2 = (const float*)d_in[10];
    const float* bm2 = (const float*)d_in[11];
    const float* Wv1 = (const float*)d_in[12];
    const float* bv1 = (const float*)d_in[13];
    const float* Wv2 = (const float*)d_in[14];
    const float* bv2 = (const float*)d_in[15];
    const float* Ws1 = (const float*)d_in[16];
    const float* bs1 = (const float*)d_in[17];
    const float* Ws2 = (const float*)d_in[18];
    const float* bs2 = (const float*)d_in[19];

    if (ws_size < WS_NEED) return;

    char* wsc = (char*)d_ws;
    short* wsb = (short*)d_ws;
    float* bm1f = (float*)(wsc + BM1F_BYTE);
    float* Zacc = (float*)(wsc + ACC_BYTE);
    float* macc = Zacc + ZACC_ELEMS;
    float* cnt  = macc + MACC_ELEMS;

    zero_kernel<<<2048, 256, 0, stream>>>(Zacc, ACC_TOTAL);
    fold_kernel<<<192, 256, 0, stream>>>(We, be, Wm1, bm1, wsb + WM1T_OFF, bm1f);
    prep_kernel<<<360, 256, 0, stream>>>(Wm2, Wv1, Wv2, Ws1, Ws2, wsb);
    edge_kernel<<<NED/EPB, 256, 0, stream>>>(Z, h, ei, edf, edv,
        wsb + WM1T_OFF, bm1f, wsb + WM2T_OFF, bm2, wsb + WV1T_OFF, bv1,
        wsb + WV2T_OFF, bv2, Zacc, macc, cnt);
    node_kernel<<<(NND + 63)/64, 256, 0, stream>>>(h, wsb + WS1T_OFF, bs1,
        wsb + WS2T_OFF, bs2, Zacc, macc, cnt, (float*)d_out);
}

// Round 8
// 1105.124 us; speedup vs baseline: 1.0589x; 1.0589x over previous
//
#include <hip/hip_runtime.h>
#include <hip/hip_bf16.h>

typedef __attribute__((ext_vector_type(8))) short s8b;     // 8 bf16 (4 VGPRs)
typedef __attribute__((ext_vector_type(4))) float f32x4;   // MFMA accumulator
typedef __attribute__((ext_vector_type(4))) unsigned u32x4;

#define NND 50000
#define NED 800000
#define EPB 128     // edges per block
#define EPW 32      // edges per wave

// workspace layout (bf16-element offsets for weights, byte offsets for f32)
#define WM1T_OFF 0         // [128][384] folded+transposed Wm1'
#define WM2T_OFF 49152     // [128][128]
#define WV1T_OFF 65536     // [128][128]
#define WV2T_OFF 81920     // [80][128]
#define WS1T_OFF 92160     // [128][256]
#define WS2T_OFF 124928    // [128][128]
#define BM1F_BYTE 282624   // 128 f32 (folded bias)
#define ACC_BYTE  283136   // f32 accumulators start (16B aligned)
#define ZACC_ELEMS (NND*48)
#define MACC_ELEMS (NND*128)
#define ACC_TOTAL (ZACC_ELEMS + MACC_ELEMS + NND)   // Zacc + macc + deg (zeroed)
#define WS_NEED (ACC_BYTE + (size_t)(ACC_TOTAL + NND + NED)*4)  // + cursor + perm

// accurate RNE cvt (weight prep only)
__device__ __forceinline__ short f2bs(float x){
    __hip_bfloat16 b = __float2bfloat16(x);
    return __builtin_bit_cast(short, b);
}
// fast cvt: round-half-up, 2 VALU ops (finite inputs only)
__device__ __forceinline__ short f2bs_fast(float x){
    unsigned u = __builtin_bit_cast(unsigned, x) + 0x8000u;
    return (short)(u >> 16);
}
// pack 2 floats -> 2 bf16 in one dword (lo=a, hi=b): add,add,v_perm = 3 ops
__device__ __forceinline__ unsigned pk2(float a, float b){
    unsigned ua = __builtin_bit_cast(unsigned, a) + 0x8000u;
    unsigned ub = __builtin_bit_cast(unsigned, b) + 0x8000u;
    return __builtin_amdgcn_perm(ub, ua, 0x07060302u);
}
__device__ __forceinline__ float bs2f(short s){
    unsigned u = ((unsigned)(unsigned short)s) << 16;
    return __builtin_bit_cast(float, u);
}
__device__ __forceinline__ float upk_lo(unsigned u){
    return __builtin_bit_cast(float, u << 16);
}
__device__ __forceinline__ float upk_hi(unsigned u){
    return __builtin_bit_cast(float, u & 0xffff0000u);
}
// silu via hardware rcp (1 ulp) — avoids the IEEE div expansion
__device__ __forceinline__ float silu_f(float x){
    float e = __expf(-x);
    return x * __builtin_amdgcn_rcpf(1.0f + e);
}

// load 8 consecutive f32 (16B-aligned) -> bf16 A/B fragment (12 VALU ops)
__device__ __forceinline__ s8b load8f_bf(const float* p){
    f32x4 a = *(const f32x4*)p;
    f32x4 b = *(const f32x4*)(p + 4);
    u32x4 r;
    r[0] = pk2(a[0], a[1]); r[1] = pk2(a[2], a[3]);
    r[2] = pk2(b[0], b[1]); r[3] = pk2(b[2], b[3]);
    return __builtin_bit_cast(s8b, r);
}

#define MFMA16(a,b,c) __builtin_amdgcn_mfma_f32_16x16x32_bf16((a),(b),(c),0,0,0)
// LDS-only ordering: do NOT drain vmcnt (atomics must free-run)
#define LDS_FENCE() asm volatile("s_waitcnt lgkmcnt(0)" ::: "memory")

// ---------------- zero accumulators (no SDMA memset — coherence with atomics) ----------------
__global__ __launch_bounds__(256) void zero_kernel(float* __restrict__ p, int n)
{
    int i = blockIdx.x*256 + threadIdx.x;
    int stride = gridDim.x*256;
    for (; i < n; i += stride) p[i] = 0.0f;
}

// ---------------- weight prep ----------------
__global__ __launch_bounds__(256) void fold_kernel(
    const float* __restrict__ We, const float* __restrict__ be,
    const float* __restrict__ Wm1, const float* __restrict__ bm1,
    short* __restrict__ Wm1T, float* __restrict__ bm1f)
{
    int idx = blockIdx.x*256 + threadIdx.x;
    if (idx >= 128*384) return;
    int n = idx / 384, k = idx - n*384;
    float v;
    if (k < 356) v = Wm1[(size_t)k*128 + n];
    else if (k < 372) {
        int j = k - 356; float s = 0.f;
        for (int c = 0; c < 128; c++)
            s += We[j*128 + c] * Wm1[(size_t)(356+c)*128 + n];
        v = s;
    } else v = 0.f;
    Wm1T[(size_t)n*384 + k] = f2bs(v);
    if (k == 0) {
        float s = bm1[n];
        for (int c = 0; c < 128; c++)
            s += be[c] * Wm1[(size_t)(356+c)*128 + n];
        bm1f[n] = s;
    }
}

__global__ __launch_bounds__(256) void prep_kernel(
    const float* __restrict__ Wm2, const float* __restrict__ Wv1,
    const float* __restrict__ Wv2, const float* __restrict__ Ws1,
    const float* __restrict__ Ws2, short* __restrict__ wsb)
{
    int i = blockIdx.x*256 + threadIdx.x;
    if (i < 16384) { int k=i>>7, n=i&127; wsb[WM2T_OFF + n*128 + k] = f2bs(Wm2[i]); return; }
    i -= 16384;
    if (i < 16384) { int k=i>>7, n=i&127; wsb[WV1T_OFF + n*128 + k] = f2bs(Wv1[i]); return; }
    i -= 16384;
    if (i < 10240) { int k=i/80, n=i-k*80; wsb[WV2T_OFF + n*128 + k] = f2bs(Wv2[i]); return; }
    i -= 10240;
    if (i < 32768) { int k=i>>7, n=i&127; wsb[WS1T_OFF + n*256 + k] = f2bs(Ws1[i]); return; }
    i -= 32768;
    if (i < 16384) { int k=i>>7, n=i&127; wsb[WS2T_OFF + n*128 + k] = f2bs(Ws2[i]); return; }
}

// ---------------- counting sort by dst: histogram -> scan -> scatter ----------------
__global__ __launch_bounds__(256) void hist_kernel(const int* __restrict__ ei, int* __restrict__ deg)
{
    int e = blockIdx.x*256 + threadIdx.x;
    if (e < NED) atomicAdd(&deg[ei[NED + e]], 1);
}

__global__ __launch_bounds__(256) void scan_kernel(const int* __restrict__ deg, int* __restrict__ cursor)
{
    __shared__ int part[256];
    const int t = threadIdx.x;
    const int beg = t*196;
    const int end = (beg + 196 < NND) ? beg + 196 : NND;
    int s = 0;
    for (int i = beg; i < end; i++) s += deg[i];
    part[t] = s;
    __syncthreads();
    if (t == 0) {
        int acc = 0;
        for (int i = 0; i < 256; i++) { int v = part[i]; part[i] = acc; acc += v; }
    }
    __syncthreads();
    int run = part[t];
    for (int i = beg; i < end; i++) { cursor[i] = run; run += deg[i]; }
}

__global__ __launch_bounds__(256) void scatter_kernel(const int* __restrict__ ei,
                                                      int* __restrict__ cursor,
                                                      int* __restrict__ perm)
{
    int e = blockIdx.x*256 + threadIdx.x;
    if (e < NED) {
        int d = ei[NED + e];
        int p = atomicAdd(&cursor[d], 1);
        perm[p] = e;
    }
}

// ---------------- edge kernel ----------------
// 128 dst-sorted edges/block, 4 waves x 32 edges (2 MFMA A-tiles).
// msg & Zagg are block-reduced by dst-run in LDS before atomics (~13x fewer atomics).
__global__ __launch_bounds__(256, 4) void edge_kernel(
    const float* __restrict__ Z, const float* __restrict__ h,
    const int* __restrict__ ei, const int* __restrict__ perm,
    const float* __restrict__ edf, const float* __restrict__ edv,
    const short* __restrict__ Wm1T, const float* __restrict__ bm1f,
    const short* __restrict__ Wm2T, const float* __restrict__ bm2,
    const short* __restrict__ Wv1T, const float* __restrict__ bv1,
    const short* __restrict__ Wv2T, const float* __restrict__ bv2,
    float* __restrict__ Zacc, float* __restrict__ macc)
{
    __shared__ __align__(16) short ssh[EPB*136];  // invar/edf -> act1 -> msg -> act3 -> Z+Zagg
    __shared__ int srcs[EPB], dsts[EPB];

    const int tid  = threadIdx.x;
    const int lane = tid & 63;
    const int wave = tid >> 6;
    const int wb   = wave * EPW;
    const int ebase= blockIdx.x * EPB;

    const int row = wb + (lane >> 1);
    const int sub = lane & 1;          // h-parity: this lane owns h = 2*sub, 2*sub+1

    // ---- Phase A1: indices + Z_ij diffs into registers (packed bf16 pairs) ----
    unsigned zp[15];    // [g=d*4+t] for t<4 ; zp[12+d] = edv pair
    {
        const int e = perm[ebase + row];
        const int s = ei[e], d = ei[NED + e];
        if (sub == 0) { srcs[row] = s; dsts[row] = d; }
        const float* Zs = Z + (size_t)s*48 + sub*24;
        const float* Zd = Z + (size_t)d*48 + sub*24;
        float dv[24];
        #pragma unroll
        for (int q = 0; q < 6; q++) {
            f32x4 a = *(const f32x4*)(Zd + q*4);
            f32x4 b = *(const f32x4*)(Zs + q*4);
            dv[q*4+0] = a[0]-b[0]; dv[q*4+1] = a[1]-b[1];
            dv[q*4+2] = a[2]-b[2]; dv[q*4+3] = a[3]-b[3];
        }
        unsigned pA[6], pB[6], rc[6];
        #pragma unroll
        for (int q = 0; q < 6; q++) {
            pA[q] = pk2(dv[q*4+0], dv[q*4+1]);   // parity 0 (h=0,1)
            pB[q] = pk2(dv[q*4+2], dv[q*4+3]);   // parity 1 (h=2,3)
        }
        #pragma unroll
        for (int q = 0; q < 6; q++)
            rc[q] = (unsigned)__shfl_xor((int)(sub ? pA[q] : pB[q]), 1);
        #pragma unroll
        for (int i = 0; i < 6; i++) zp[i]   = sub ? rc[i] : pA[i];
        #pragma unroll
        for (int i = 0; i < 6; i++) zp[6+i] = sub ? pB[i] : rc[i];
        float e0 = edv[(size_t)e*3+0], e1 = edv[(size_t)e*3+1], e2 = edv[(size_t)e*3+2];
        zp[12] = pk2(e0,e0); zp[13] = pk2(e1,e1); zp[14] = pk2(e2,e2);

        // ---- Phase A2: invariants (register-local Gram, h-diagonal) + edf stage ----
        float zt0[15], zt1[15];
        #pragma unroll
        for (int i = 0; i < 15; i++) { zt0[i] = upk_lo(zp[i]); zt1[i] = upk_hi(zp[i]); }
        const int PT[15] = {0,0,0,0,0,1,1,1,1,2,2,2,3,3,4};
        const int PR[15] = {0,1,2,3,4,1,2,3,4,2,3,4,3,4,4};
        float v0[15], v1[15];
        float ssql = 0.f;
        #pragma unroll
        for (int k = 0; k < 15; k++) {
            const int tt = PT[k], rr = PR[k];
            float a0 = 0.f, a1 = 0.f;
            #pragma unroll
            for (int d2 = 0; d2 < 3; d2++) {
                const int gt = (tt < 4) ? d2*4 + tt : 12 + d2;
                const int gr = (rr < 4) ? d2*4 + rr : 12 + d2;
                a0 += zt0[gt]*zt0[gr];
                a1 += zt1[gt]*zt1[gr];
            }
            v0[k] = a0; v1[k] = a1;
            const float w = (tt == rr) ? 1.0f : 2.0f;
            ssql += w*(a0*a0 + a1*a1);
        }
        float ssq = ssql + __shfl_xor(ssql, 1);
        const float rn = __builtin_amdgcn_rsqf(fmaxf(ssq, 1e-24f));
        #pragma unroll
        for (int k = 0; k < 15; k++) {
            const int tt = PT[k], rr = PR[k];
            unsigned pkv = pk2(v0[k]*rn, v1[k]*rn);
            *(unsigned*)(&ssh[row*136 + tt*20 + rr*4 + 2*sub]) = pkv;
            if (tt != rr)
                *(unsigned*)(&ssh[row*136 + rr*20 + tt*4 + 2*sub]) = pkv;
        }
        {
            const float* ep = edf + (size_t)e*16 + sub*8;
            f32x4 f0 = *(const f32x4*)ep, f1 = *(const f32x4*)(ep+4);
            int cb = row*136 + 100 + sub*8;
            *(unsigned*)(&ssh[cb+0]) = pk2(f0[0], f0[1]);
            *(unsigned*)(&ssh[cb+2]) = pk2(f0[2], f0[3]);
            *(unsigned*)(&ssh[cb+4]) = pk2(f1[0], f1[1]);
            *(unsigned*)(&ssh[cb+6]) = pk2(f1[2], f1[3]);
        }
        #pragma unroll
        for (int k = 0; k < 5; k++)
            *(unsigned*)(&ssh[row*136 + 116 + (sub*5 + k)*2]) = 0;
    }
    LDS_FENCE();

    // ---- GEMM phase: 2 A-tiles (32 edges) share every B-fragment load ----
    const int quad = lane >> 4;
    const int c15  = lane & 15;
    const int rA0  = wb + c15;
    const int rA1  = wb + 16 + c15;
    const float* hd0 = h + (size_t)dsts[rA0]*128 + quad*8;
    const float* hs0 = h + (size_t)srcs[rA0]*128 + quad*8;
    const float* hd1 = h + (size_t)dsts[rA1]*128 + quad*8;
    const float* hs1 = h + (size_t)srcs[rA1]*128 + quad*8;
    const short* sA0 = ssh + rA0*136 + quad*8;
    const short* sA1 = ssh + rA1*136 + quad*8;
    const f32x4 z4 = {0.f,0.f,0.f,0.f};

    // Layer 1: x'[384] @ Wm1T' -> 128
    f32x4 acc1[2][8];
    #pragma unroll
    for (int nt = 0; nt < 8; nt++) { acc1[0][nt] = z4; acc1[1][nt] = z4; }
    {
        const short* Bp = Wm1T + (size_t)c15*384 + quad*8;
        #pragma unroll
        for (int ks = 0; ks < 12; ks++) {
            s8b a0, a1;
            if (ks < 4)      { a0 = load8f_bf(hd0 + ks*32);     a1 = load8f_bf(hd1 + ks*32); }
            else if (ks < 8) { a0 = load8f_bf(hs0 + (ks-4)*32); a1 = load8f_bf(hs1 + (ks-4)*32); }
            else             { a0 = *(const s8b*)(sA0 + (ks-8)*32); a1 = *(const s8b*)(sA1 + (ks-8)*32); }
            #pragma unroll
            for (int nt = 0; nt < 8; nt++) {
                s8b b = *(const s8b*)(Bp + nt*(16*384) + ks*32);
                acc1[0][nt] = MFMA16(a0, b, acc1[0][nt]);
                acc1[1][nt] = MFMA16(a1, b, acc1[1][nt]);
            }
        }
    }
    LDS_FENCE();
    #pragma unroll
    for (int nt = 0; nt < 8; nt++) {
        const int col = nt*16 + c15;
        const float bias = bm1f[col];
        #pragma unroll
        for (int tl = 0; tl < 2; tl++)
            #pragma unroll
            for (int r = 0; r < 4; r++)
                ssh[(wb + tl*16 + quad*4 + r)*136 + col] = f2bs_fast(silu_f(acc1[tl][nt][r] + bias));
    }
    LDS_FENCE();

    // Layer 2: act1 @ Wm2 -> msg (LDS only; reduction pass does the atomics)
    f32x4 acc2[2][8];
    #pragma unroll
    for (int nt = 0; nt < 8; nt++) { acc2[0][nt] = z4; acc2[1][nt] = z4; }
    {
        const short* Bp = Wm2T + (size_t)c15*128 + quad*8;
        #pragma unroll
        for (int ks = 0; ks < 4; ks++) {
            s8b a0 = *(const s8b*)(sA0 + ks*32);
            s8b a1 = *(const s8b*)(sA1 + ks*32);
            #pragma unroll
            for (int nt = 0; nt < 8; nt++) {
                s8b b = *(const s8b*)(Bp + nt*(16*128) + ks*32);
                acc2[0][nt] = MFMA16(a0, b, acc2[0][nt]);
                acc2[1][nt] = MFMA16(a1, b, acc2[1][nt]);
            }
        }
    }
    LDS_FENCE();
    #pragma unroll
    for (int nt = 0; nt < 8; nt++) {
        const int col = nt*16 + c15;
        const float bias = bm2[col];
        #pragma unroll
        for (int tl = 0; tl < 2; tl++)
            #pragma unroll
            for (int r = 0; r < 4; r++) {
                const int rw = wb + tl*16 + quad*4 + r;
                ssh[rw*136 + col] = f2bs_fast(silu_f(acc2[tl][nt][r] + bias));
            }
    }
    __syncthreads();

    // ---- macc segmented reduction: dst-sorted rows -> ~1 atomic per run per col ----
    {
        const int col = tid & 127;
        const int rbeg = (tid >> 7) * 64;
        float run = 0.f;
        int cur = dsts[rbeg];
        for (int r2 = rbeg; r2 < rbeg + 64; r2++) {
            int d2 = dsts[r2];
            if (d2 != cur) {
                atomicAdd(macc + (size_t)cur*128 + col, run);
                run = 0.f; cur = d2;
            }
            run += bs2f(ssh[r2*136 + col]);
        }
        atomicAdd(macc + (size_t)cur*128 + col, run);
    }
    __syncthreads();

    // Layer 3: msg @ Wv1 -> act3
    f32x4 acc3[2][8];
    #pragma unroll
    for (int nt = 0; nt < 8; nt++) { acc3[0][nt] = z4; acc3[1][nt] = z4; }
    {
        const short* Bp = Wv1T + (size_t)c15*128 + quad*8;
        #pragma unroll
        for (int ks = 0; ks < 4; ks++) {
            s8b a0 = *(const s8b*)(sA0 + ks*32);
            s8b a1 = *(const s8b*)(sA1 + ks*32);
            #pragma unroll
            for (int nt = 0; nt < 8; nt++) {
                s8b b = *(const s8b*)(Bp + nt*(16*128) + ks*32);
                acc3[0][nt] = MFMA16(a0, b, acc3[0][nt]);
                acc3[1][nt] = MFMA16(a1, b, acc3[1][nt]);
            }
        }
    }
    LDS_FENCE();
    #pragma unroll
    for (int nt = 0; nt < 8; nt++) {
        const int col = nt*16 + c15;
        const float bias = bv1[col];
        #pragma unroll
        for (int tl = 0; tl < 2; tl++)
            #pragma unroll
            for (int r = 0; r < 4; r++)
                ssh[(wb + tl*16 + quad*4 + r)*136 + col] = f2bs_fast(silu_f(acc3[tl][nt][r] + bias));
    }
    LDS_FENCE();

    // Layer 4: act3 @ Wv2 -> basis[80]
    f32x4 acc4[2][5];
    #pragma unroll
    for (int nt = 0; nt < 5; nt++) { acc4[0][nt] = z4; acc4[1][nt] = z4; }
    {
        const short* Bp = Wv2T + (size_t)c15*128 + quad*8;
        #pragma unroll
        for (int ks = 0; ks < 4; ks++) {
            s8b a0 = *(const s8b*)(sA0 + ks*32);
            s8b a1 = *(const s8b*)(sA1 + ks*32);
            #pragma unroll
            for (int nt = 0; nt < 5; nt++) {
                s8b b = *(const s8b*)(Bp + nt*(16*128) + ks*32);
                acc4[0][nt] = MFMA16(a0, b, acc4[0][nt]);
                acc4[1][nt] = MFMA16(a1, b, acc4[1][nt]);
            }
        }
    }
    // act3 dead -> restage Z_ij from registers into ssh cols 0..59 (own rows)
    LDS_FENCE();
    {
        #pragma unroll
        for (int d2 = 0; d2 < 3; d2++) {
            #pragma unroll
            for (int t = 0; t < 4; t++)
                *(unsigned*)(&ssh[row*136 + d2*20 + t*4 + 2*sub]) = zp[d2*4 + t];
            *(unsigned*)(&ssh[row*136 + d2*20 + 16 + 2*sub]) = zp[12 + d2];
        }
    }
    LDS_FENCE();
    // contract with Z_ij ; stage Zagg (bf16) into ssh cols 64..111 (own rows)
    {
        const int hh = c15 & 3;                   // basis col = t*16 + (k*4+h); c15 = k*4+h
        float bs[5];
        #pragma unroll
        for (int t = 0; t < 5; t++) bs[t] = bv2[t*16 + c15];
        #pragma unroll
        for (int tl = 0; tl < 2; tl++)
            #pragma unroll
            for (int r = 0; r < 4; r++) {
                const int rw = wb + tl*16 + quad*4 + r;
                float bt[5];
                #pragma unroll
                for (int t = 0; t < 5; t++) bt[t] = acc4[tl][t][r] + bs[t];
                #pragma unroll
                for (int dd = 0; dd < 3; dd++) {
                    float s0 = 0.f;
                    #pragma unroll
                    for (int t = 0; t < 5; t++)
                        s0 += bs2f(ssh[rw*136 + dd*20 + t*4 + hh]) * bt[t];
                    ssh[rw*136 + 64 + dd*16 + c15] = f2bs_fast(s0);
                }
            }
    }
    __syncthreads();

    // ---- Zacc segmented reduction: 48 cols, 4 row-quarters of 32 ----
    {
        const int colz = lane;
        if (colz < 48) {
            const int rbeg = wave * 32;
            float run = 0.f;
            int cur = dsts[rbeg];
            for (int r2 = rbeg; r2 < rbeg + 32; r2++) {
                int d2 = dsts[r2];
                if (d2 != cur) {
                    atomicAdd(Zacc + (size_t)cur*48 + colz, run);
                    run = 0.f; cur = d2;
                }
                run += bs2f(ssh[r2*136 + 64 + colz]);
            }
            atomicAdd(Zacc + (size_t)cur*48 + colz, run);
        }
    }
}

// ---------------- node kernel ----------------
__global__ __launch_bounds__(256) void node_kernel(
    const float* __restrict__ h,
    const short* __restrict__ Ws1T, const float* __restrict__ bs1,
    const short* __restrict__ Ws2T, const float* __restrict__ bs2,
    const float* __restrict__ Zacc, const float* __restrict__ macc,
    const int* __restrict__ deg, float* __restrict__ out)
{
    __shared__ __align__(16) short ssh[64*136];   // m stage -> act1
    const int tid = threadIdx.x, lane = tid & 63, wave = tid >> 6;
    const int mb = wave*16;
    const int nbase = blockIdx.x * 64;

    // Z_out = Zacc / max(deg,1)
    for (int i = tid; i < 64*48; i += 256) {
        int nl = i / 48, c2 = i - nl*48;
        int nd = nbase + nl;
        if (nd < NND) {
            float ct = fmaxf((float)deg[nd], 1.0f);
            out[(size_t)nd*48 + c2] = Zacc[(size_t)nd*48 + c2] / ct;
        }
    }

    // stage m (bf16), wave-private rows
    {
        const int row = mb + (lane >> 2);
        const int sub = lane & 3;
        int nd = nbase + row; if (nd >= NND) nd = 0;
        const float* mr = macc + (size_t)nd*128 + sub*32;
        #pragma unroll
        for (int j = 0; j < 8; j++) {
            f32x4 v = *(const f32x4*)(mr + j*4);
            int cb = row*136 + sub*32 + j*4;
            *(unsigned*)(&ssh[cb+0]) = pk2(v[0], v[1]);
            *(unsigned*)(&ssh[cb+2]) = pk2(v[2], v[3]);
        }
    }
    LDS_FENCE();

    const int quad = lane >> 4, c15 = lane & 15;
    const int rA = mb + c15;
    int ndA = nbase + rA; if (ndA >= NND) ndA = 0;   // clamp; stores guarded
    const float* hA = h + (size_t)ndA*128 + quad*8;
    const short* sA = ssh + rA*136 + quad*8;
    const f32x4 z4 = {0.f,0.f,0.f,0.f};

    // GEMM1: [h | m] (K=256) @ Ws1
    f32x4 acc1[8];
    #pragma unroll
    for (int nt = 0; nt < 8; nt++) acc1[nt] = z4;
    {
        const short* Bp = Ws1T + (size_t)c15*256 + quad*8;
        #pragma unroll
        for (int ks = 0; ks < 8; ks++) {
            s8b a;
            if (ks < 4) a = load8f_bf(hA + ks*32);
            else        a = *(const s8b*)(sA + (ks-4)*32);
            #pragma unroll
            for (int nt = 0; nt < 8; nt++) {
                s8b b = *(const s8b*)(Bp + nt*(16*256) + ks*32);
                acc1[nt] = MFMA16(a, b, acc1[nt]);
            }
        }
    }
    LDS_FENCE();
    #pragma unroll
    for (int nt = 0; nt < 8; nt++) {
        const int col = nt*16 + c15;
        const float bias = bs1[col];
        #pragma unroll
        for (int r = 0; r < 4; r++)
            ssh[(mb + quad*4 + r)*136 + col] = f2bs_fast(silu_f(acc1[nt][r] + bias));
    }
    LDS_FENCE();

    // GEMM2: act @ Ws2 -> h_out
    f32x4 acc2[8];
    #pragma unroll
    for (int nt = 0; nt < 8; nt++) acc2[nt] = z4;
    {
        const short* Bp = Ws2T + (size_t)c15*128 + quad*8;
        #pragma unroll
        for (int ks = 0; ks < 4; ks++) {
            s8b a = *(const s8b*)(sA + ks*32);
            #pragma unroll
            for (int nt = 0; nt < 8; nt++) {
                s8b b = *(const s8b*)(Bp + nt*(16*128) + ks*32);
                acc2[nt] = MFMA16(a, b, acc2[nt]);
            }
        }
    }
    {
        float* oh = out + (size_t)NND*48;
        #pragma unroll
        for (int nt = 0; nt < 8; nt++) {
            const int col = nt*16 + c15;
            const float bias = bs2[col];
            #pragma unroll
            for (int r = 0; r < 4; r++) {
                const int rw = mb + quad*4 + r;
                const int nd = nbase + rw;
                if (nd < NND)
                    oh[(size_t)nd*128 + col] = acc2[nt][r] + bias;
            }
        }
    }
}

extern "C" void kernel_launch(void* const* d_in, const int* in_sizes, int n_in,
                              void* d_out, int out_size, void* d_ws, size_t ws_size,
                              hipStream_t stream)
{
    const float* Z   = (const float*)d_in[0];
    const float* h   = (const float*)d_in[1];
    const int*   ei  = (const int*)d_in[2];
    const float* edf = (const float*)d_in[3];
    const float* edv = (const float*)d_in[4];
    // d_in[5] = edge_distance (unused by reference)
    const float* We  = (const float*)d_in[6];
    const float* be  = (const float*)d_in[7];
    const float* Wm1 = (const float*)d_in[8];
    const float* bm1 = (const float*)d_in[9];
    const float* Wm2 = (const float*)d_in[10];
    const float* bm2 = (const float*)d_in[11];
    const float* Wv1 = (const float*)d_in[12];
    const float* bv1 = (const float*)d_in[13];
    const float* Wv2 = (const float*)d_in[14];
    const float* bv2 = (const float*)d_in[15];
    const float* Ws1 = (const float*)d_in[16];
    const float* bs1 = (const float*)d_in[17];
    const float* Ws2 = (const float*)d_in[18];
    const float* bs2 = (const float*)d_in[19];

    if (ws_size < WS_NEED) return;

    char* wsc = (char*)d_ws;
    short* wsb = (short*)d_ws;
    float* bm1f = (float*)(wsc + BM1F_BYTE);
    float* Zacc = (float*)(wsc + ACC_BYTE);
    float* macc = Zacc + ZACC_ELEMS;
    int*   deg  = (int*)(macc + MACC_ELEMS);
    int*   cursor = deg + NND;
    int*   perm   = cursor + NND;

    zero_kernel<<<2048, 256, 0, stream>>>(Zacc, ACC_TOTAL);   // Zacc + macc + deg
    fold_kernel<<<192, 256, 0, stream>>>(We, be, Wm1, bm1, wsb + WM1T_OFF, bm1f);
    prep_kernel<<<360, 256, 0, stream>>>(Wm2, Wv1, Wv2, Ws1, Ws2, wsb);
    hist_kernel<<<(NED + 255)/256, 256, 0, stream>>>(ei, deg);
    scan_kernel<<<1, 256, 0, stream>>>(deg, cursor);
    scatter_kernel<<<(NED + 255)/256, 256, 0, stream>>>(ei, cursor, perm);
    edge_kernel<<<NED/EPB, 256, 0, stream>>>(Z, h, ei, perm, edf, edv,
        wsb + WM1T_OFF, bm1f, wsb + WM2T_OFF, bm2, wsb + WV1T_OFF, bv1,
        wsb + WV2T_OFF, bv2, Zacc, macc);
    node_kernel<<<(NND + 63)/64, 256, 0, stream>>>(h, wsb + WS1T_OFF, bs1,
        wsb + WS2T_OFF, bs2, Zacc, macc, deg, (float*)d_out);
}

// Round 9
// 1002.663 us; speedup vs baseline: 1.1671x; 1.1022x over previous
//
#include <hip/hip_runtime.h>
#include <hip/hip_bf16.h>

typedef __attribute__((ext_vector_type(8))) short s8b;     // 8 bf16 (4 VGPRs)
typedef __attribute__((ext_vector_type(4))) float f32x4;   // MFMA accumulator
typedef __attribute__((ext_vector_type(4))) unsigned u32x4;

#define NND 50000
#define NED 800000
#define EPB 128     // edges per block
#define EPW 32      // edges per wave
#define SCH 200     // scan chunks
#define SCS 250     // chunk size: 200*250 = 50000

// workspace layout (bf16-element offsets for weights, byte offsets for f32)
#define WM1T_OFF 0         // [128][384] folded+transposed Wm1'
#define WM2T_OFF 49152     // [128][128]
#define WV1T_OFF 65536     // [128][128]
#define WV2T_OFF 81920     // [80][128]
#define WS1T_OFF 92160     // [128][256]
#define WS2T_OFF 124928    // [128][128]
#define BM1F_BYTE 282624   // 128 f32 (folded bias)
#define ACC_BYTE  283136   // f32 accumulators start (16B aligned)
#define ZACC_ELEMS (NND*48)
#define MACC_ELEMS (NND*128)
#define ACC_TOTAL (ZACC_ELEMS + MACC_ELEMS + NND)   // Zacc + macc + deg (zeroed)
// ints after acc: cursor[NND], perm[NED], part[256]
#define WS_MIN  (ACC_BYTE + (size_t)(ACC_TOTAL + NND + NED + 256)*4)
// optional bf16 staging: h_bf [NND*128], Z_bf [NND*48]
#define HB_BYTE  ((WS_MIN + 15) & ~(size_t)15)
#define ZB_BYTE  (HB_BYTE + (size_t)NND*128*2)
#define WS_FULL  (ZB_BYTE + (size_t)NND*48*2)

// accurate RNE cvt (prep only)
__device__ __forceinline__ short f2bs(float x){
    __hip_bfloat16 b = __float2bfloat16(x);
    return __builtin_bit_cast(short, b);
}
// fast cvt: round-half-up, 2 VALU ops (finite inputs only)
__device__ __forceinline__ short f2bs_fast(float x){
    unsigned u = __builtin_bit_cast(unsigned, x) + 0x8000u;
    return (short)(u >> 16);
}
// pack 2 floats -> 2 bf16 in one dword (lo=a, hi=b)
__device__ __forceinline__ unsigned pk2(float a, float b){
    unsigned ua = __builtin_bit_cast(unsigned, a) + 0x8000u;
    unsigned ub = __builtin_bit_cast(unsigned, b) + 0x8000u;
    return __builtin_amdgcn_perm(ub, ua, 0x07060302u);
}
__device__ __forceinline__ float bs2f(short s){
    unsigned u = ((unsigned)(unsigned short)s) << 16;
    return __builtin_bit_cast(float, u);
}
__device__ __forceinline__ float upk_lo(unsigned u){
    return __builtin_bit_cast(float, u << 16);
}
__device__ __forceinline__ float upk_hi(unsigned u){
    return __builtin_bit_cast(float, u & 0xffff0000u);
}
__device__ __forceinline__ float silu_f(float x){
    float e = __expf(-x);
    return x * __builtin_amdgcn_rcpf(1.0f + e);
}
// load 8 consecutive f32 (16B-aligned) -> bf16 fragment
__device__ __forceinline__ s8b load8f_bf(const float* p){
    f32x4 a = *(const f32x4*)p;
    f32x4 b = *(const f32x4*)(p + 4);
    u32x4 r;
    r[0] = pk2(a[0], a[1]); r[1] = pk2(a[2], a[3]);
    r[2] = pk2(b[0], b[1]); r[3] = pk2(b[2], b[3]);
    return __builtin_bit_cast(s8b, r);
}

#define MFMA16(a,b,c) __builtin_amdgcn_mfma_f32_16x16x32_bf16((a),(b),(c),0,0,0)
#define LDS_FENCE() asm volatile("s_waitcnt lgkmcnt(0)" ::: "memory")

// ---------------- zero / cvt ----------------
__global__ __launch_bounds__(256) void zero_kernel(float* __restrict__ p, int n)
{
    int i = blockIdx.x*256 + threadIdx.x;
    int stride = gridDim.x*256;
    for (; i < n; i += stride) p[i] = 0.0f;
}
__global__ __launch_bounds__(256) void cvt_kernel(const float* __restrict__ src,
                                                  short* __restrict__ dst, int n)
{
    int i = blockIdx.x*256 + threadIdx.x;
    int stride = gridDim.x*256;
    for (; i < n; i += stride) dst[i] = f2bs(src[i]);
}

// ---------------- weight prep ----------------
__global__ __launch_bounds__(256) void fold_kernel(
    const float* __restrict__ We, const float* __restrict__ be,
    const float* __restrict__ Wm1, const float* __restrict__ bm1,
    short* __restrict__ Wm1T, float* __restrict__ bm1f)
{
    int idx = blockIdx.x*256 + threadIdx.x;
    if (idx >= 128*384) return;
    int n = idx / 384, k = idx - n*384;
    float v;
    if (k < 356) v = Wm1[(size_t)k*128 + n];
    else if (k < 372) {
        int j = k - 356; float s = 0.f;
        for (int c = 0; c < 128; c++)
            s += We[j*128 + c] * Wm1[(size_t)(356+c)*128 + n];
        v = s;
    } else v = 0.f;
    Wm1T[(size_t)n*384 + k] = f2bs(v);
    if (k == 0) {
        float s = bm1[n];
        for (int c = 0; c < 128; c++)
            s += be[c] * Wm1[(size_t)(356+c)*128 + n];
        bm1f[n] = s;
    }
}

__global__ __launch_bounds__(256) void prep_kernel(
    const float* __restrict__ Wm2, const float* __restrict__ Wv1,
    const float* __restrict__ Wv2, const float* __restrict__ Ws1,
    const float* __restrict__ Ws2, short* __restrict__ wsb)
{
    int i = blockIdx.x*256 + threadIdx.x;
    if (i < 16384) { int k=i>>7, n=i&127; wsb[WM2T_OFF + n*128 + k] = f2bs(Wm2[i]); return; }
    i -= 16384;
    if (i < 16384) { int k=i>>7, n=i&127; wsb[WV1T_OFF + n*128 + k] = f2bs(Wv1[i]); return; }
    i -= 16384;
    if (i < 10240) { int k=i/80, n=i-k*80; wsb[WV2T_OFF + n*128 + k] = f2bs(Wv2[i]); return; }
    i -= 10240;
    if (i < 32768) { int k=i>>7, n=i&127; wsb[WS1T_OFF + n*256 + k] = f2bs(Ws1[i]); return; }
    i -= 32768;
    if (i < 16384) { int k=i>>7, n=i&127; wsb[WS2T_OFF + n*128 + k] = f2bs(Ws2[i]); return; }
}

// ---------------- counting sort by dst ----------------
__global__ __launch_bounds__(256) void hist_kernel(const int* __restrict__ ei, int* __restrict__ deg)
{
    int e = blockIdx.x*256 + threadIdx.x;
    if (e < NED) atomicAdd(&deg[ei[NED + e]], 1);
}

__global__ __launch_bounds__(256) void scan1_kernel(const int* __restrict__ deg, int* __restrict__ part)
{
    __shared__ int red[256];
    int b = blockIdx.x, t = threadIdx.x;
    red[t] = (t < SCS) ? deg[b*SCS + t] : 0;
    __syncthreads();
    for (int s = 128; s > 0; s >>= 1) {
        if (t < s) red[t] += red[t+s];
        __syncthreads();
    }
    if (t == 0) part[b] = red[0];
}
__global__ __launch_bounds__(64) void scan2_kernel(int* __restrict__ part)
{
    if (threadIdx.x == 0) {
        int acc = 0;
        for (int i = 0; i < SCH; i++) { int v = part[i]; part[i] = acc; acc += v; }
    }
}
__global__ __launch_bounds__(256) void scan3_kernel(const int* __restrict__ deg,
                                                    const int* __restrict__ part,
                                                    int* __restrict__ cursor)
{
    __shared__ int buf[256];
    int b = blockIdx.x, t = threadIdx.x;
    int v = (t < SCS) ? deg[b*SCS + t] : 0;
    buf[t] = v;
    __syncthreads();
    for (int s = 1; s < 256; s <<= 1) {
        int add = (t >= s) ? buf[t-s] : 0;
        __syncthreads();
        buf[t] += add;
        __syncthreads();
    }
    if (t < SCS) cursor[b*SCS + t] = part[b] + buf[t] - v;   // exclusive
}

__global__ __launch_bounds__(256) void scatter_kernel(const int* __restrict__ ei,
                                                      int* __restrict__ cursor,
                                                      int* __restrict__ perm)
{
    int e = blockIdx.x*256 + threadIdx.x;
    if (e < NED) {
        int d = ei[NED + e];
        int p = atomicAdd(&cursor[d], 1);
        perm[p] = e;
    }
}

// ---------------- edge kernel ----------------
// 128 dst-sorted edges/block, 4 waves x 32 edges (2 MFMA A-tiles).
// Everything wave-private: NO __syncthreads, only lgkm fences.
// BF=1: h/Z read from bf16-staged copies (halved gather bytes, no cvt).
template<int BF>
__global__ __launch_bounds__(256, 4) void edge_kernel(
    const float* __restrict__ Z, const float* __restrict__ h,
    const short* __restrict__ Zb, const short* __restrict__ hb,
    const int* __restrict__ ei, const int* __restrict__ perm,
    const float* __restrict__ edf, const float* __restrict__ edv,
    const short* __restrict__ Wm1T, const float* __restrict__ bm1f,
    const short* __restrict__ Wm2T, const float* __restrict__ bm2,
    const short* __restrict__ Wv1T, const float* __restrict__ bv1,
    const short* __restrict__ Wv2T, const float* __restrict__ bv2,
    float* __restrict__ Zacc, float* __restrict__ macc)
{
    __shared__ __align__(16) short ssh[EPB*136];  // invar/edf -> act1 -> msg -> act3 -> Z+Zagg
    __shared__ int srcs[EPB], dsts[EPB];

    const int tid  = threadIdx.x;
    const int lane = tid & 63;
    const int wave = tid >> 6;
    const int wb   = wave * EPW;
    const int ebase= blockIdx.x * EPB;

    const int row = wb + (lane >> 1);
    const int sub = lane & 1;          // h-parity: this lane owns h = 2*sub, 2*sub+1

    // ---- Phase A: indices + Z_ij diffs (packed bf16 pairs) + invariants ----
    unsigned zp[15];    // [g=d*4+t] for t<4 ; zp[12+d] = edv pair
    {
        const int e = perm[ebase + row];
        const int s = ei[e], d = ei[NED + e];
        if (sub == 0) { srcs[row] = s; dsts[row] = d; }
        unsigned pA[6], pB[6], rc[6];
        if (BF) {
            const s8b zd0 = *(const s8b*)(Zb + (size_t)d*48 + sub*24);
            const s8b zd1 = *(const s8b*)(Zb + (size_t)d*48 + sub*24 + 8);
            const s8b zd2 = *(const s8b*)(Zb + (size_t)d*48 + sub*24 + 16);
            const s8b zs0 = *(const s8b*)(Zb + (size_t)s*48 + sub*24);
            const s8b zs1 = *(const s8b*)(Zb + (size_t)s*48 + sub*24 + 8);
            const s8b zs2 = *(const s8b*)(Zb + (size_t)s*48 + sub*24 + 16);
            u32x4 ud01 = __builtin_bit_cast(u32x4, zd0);
            u32x4 ud23 = __builtin_bit_cast(u32x4, zd1);
            u32x4 ud45 = __builtin_bit_cast(u32x4, zd2);
            u32x4 us01 = __builtin_bit_cast(u32x4, zs0);
            u32x4 us23 = __builtin_bit_cast(u32x4, zs1);
            u32x4 us45 = __builtin_bit_cast(u32x4, zs2);
            unsigned ud[12], us[12];
            #pragma unroll
            for (int j = 0; j < 4; j++) {
                ud[j] = ud01[j]; ud[4+j] = ud23[j]; ud[8+j] = ud45[j];
                us[j] = us01[j]; us[4+j] = us23[j]; us[8+j] = us45[j];
            }
            #pragma unroll
            for (int q = 0; q < 6; q++) {
                float l0 = upk_lo(ud[2*q])   - upk_lo(us[2*q]);
                float h0 = upk_hi(ud[2*q])   - upk_hi(us[2*q]);
                float l1 = upk_lo(ud[2*q+1]) - upk_lo(us[2*q+1]);
                float h1 = upk_hi(ud[2*q+1]) - upk_hi(us[2*q+1]);
                pA[q] = pk2(l0, h0);
                pB[q] = pk2(l1, h1);
            }
        } else {
            const float* Zs = Z + (size_t)s*48 + sub*24;
            const float* Zd = Z + (size_t)d*48 + sub*24;
            float dv[24];
            #pragma unroll
            for (int q = 0; q < 6; q++) {
                f32x4 a = *(const f32x4*)(Zd + q*4);
                f32x4 b = *(const f32x4*)(Zs + q*4);
                dv[q*4+0] = a[0]-b[0]; dv[q*4+1] = a[1]-b[1];
                dv[q*4+2] = a[2]-b[2]; dv[q*4+3] = a[3]-b[3];
            }
            #pragma unroll
            for (int q = 0; q < 6; q++) {
                pA[q] = pk2(dv[q*4+0], dv[q*4+1]);
                pB[q] = pk2(dv[q*4+2], dv[q*4+3]);
            }
        }
        #pragma unroll
        for (int q = 0; q < 6; q++)
            rc[q] = (unsigned)__shfl_xor((int)(sub ? pA[q] : pB[q]), 1);
        #pragma unroll
        for (int i = 0; i < 6; i++) zp[i]   = sub ? rc[i] : pA[i];
        #pragma unroll
        for (int i = 0; i < 6; i++) zp[6+i] = sub ? pB[i] : rc[i];
        float e0 = edv[(size_t)e*3+0], e1 = edv[(size_t)e*3+1], e2 = edv[(size_t)e*3+2];
        zp[12] = pk2(e0,e0); zp[13] = pk2(e1,e1); zp[14] = pk2(e2,e2);

        // invariants (register-local Gram, h-diagonal)
        float zt0[15], zt1[15];
        #pragma unroll
        for (int i = 0; i < 15; i++) { zt0[i] = upk_lo(zp[i]); zt1[i] = upk_hi(zp[i]); }
        const int PT[15] = {0,0,0,0,0,1,1,1,1,2,2,2,3,3,4};
        const int PR[15] = {0,1,2,3,4,1,2,3,4,2,3,4,3,4,4};
        float v0[15], v1[15];
        float ssql = 0.f;
        #pragma unroll
        for (int k = 0; k < 15; k++) {
            const int tt = PT[k], rr = PR[k];
            float a0 = 0.f, a1 = 0.f;
            #pragma unroll
            for (int d2 = 0; d2 < 3; d2++) {
                const int gt = (tt < 4) ? d2*4 + tt : 12 + d2;
                const int gr = (rr < 4) ? d2*4 + rr : 12 + d2;
                a0 += zt0[gt]*zt0[gr];
                a1 += zt1[gt]*zt1[gr];
            }
            v0[k] = a0; v1[k] = a1;
            const float w = (tt == rr) ? 1.0f : 2.0f;
            ssql += w*(a0*a0 + a1*a1);
        }
        float ssq = ssql + __shfl_xor(ssql, 1);
        const float rn = __builtin_amdgcn_rsqf(fmaxf(ssq, 1e-24f));
        #pragma unroll
        for (int k = 0; k < 15; k++) {
            const int tt = PT[k], rr = PR[k];
            unsigned pkv = pk2(v0[k]*rn, v1[k]*rn);
            *(unsigned*)(&ssh[row*136 + tt*20 + rr*4 + 2*sub]) = pkv;
            if (tt != rr)
                *(unsigned*)(&ssh[row*136 + rr*20 + tt*4 + 2*sub]) = pkv;
        }
        {
            const float* ep = edf + (size_t)e*16 + sub*8;
            f32x4 f0 = *(const f32x4*)ep, f1 = *(const f32x4*)(ep+4);
            int cb = row*136 + 100 + sub*8;
            *(unsigned*)(&ssh[cb+0]) = pk2(f0[0], f0[1]);
            *(unsigned*)(&ssh[cb+2]) = pk2(f0[2], f0[3]);
            *(unsigned*)(&ssh[cb+4]) = pk2(f1[0], f1[1]);
            *(unsigned*)(&ssh[cb+6]) = pk2(f1[2], f1[3]);
        }
        #pragma unroll
        for (int k = 0; k < 5; k++)
            *(unsigned*)(&ssh[row*136 + 116 + (sub*5 + k)*2]) = 0;
    }
    LDS_FENCE();

    // ---- GEMM phase: 2 A-tiles (32 edges) share every B-fragment load ----
    const int quad = lane >> 4;
    const int c15  = lane & 15;
    const int rA0  = wb + c15;
    const int rA1  = wb + 16 + c15;
    const short* sA0 = ssh + rA0*136 + quad*8;
    const short* sA1 = ssh + rA1*136 + quad*8;
    const f32x4 z4 = {0.f,0.f,0.f,0.f};

    // Layer 1: x'[384] @ Wm1T' -> 128
    f32x4 acc1[2][8];
    #pragma unroll
    for (int nt = 0; nt < 8; nt++) { acc1[0][nt] = z4; acc1[1][nt] = z4; }
    {
        const short* Bp = Wm1T + (size_t)c15*384 + quad*8;
        if (BF) {
            const short* hd0 = hb + (size_t)dsts[rA0]*128 + quad*8;
            const short* hs0 = hb + (size_t)srcs[rA0]*128 + quad*8;
            const short* hd1 = hb + (size_t)dsts[rA1]*128 + quad*8;
            const short* hs1 = hb + (size_t)srcs[rA1]*128 + quad*8;
            #pragma unroll
            for (int ks = 0; ks < 12; ks++) {
                s8b a0, a1;
                if (ks < 4)      { a0 = *(const s8b*)(hd0 + ks*32);     a1 = *(const s8b*)(hd1 + ks*32); }
                else if (ks < 8) { a0 = *(const s8b*)(hs0 + (ks-4)*32); a1 = *(const s8b*)(hs1 + (ks-4)*32); }
                else             { a0 = *(const s8b*)(sA0 + (ks-8)*32); a1 = *(const s8b*)(sA1 + (ks-8)*32); }
                #pragma unroll
                for (int nt = 0; nt < 8; nt++) {
                    s8b b = *(const s8b*)(Bp + nt*(16*384) + ks*32);
                    acc1[0][nt] = MFMA16(a0, b, acc1[0][nt]);
                    acc1[1][nt] = MFMA16(a1, b, acc1[1][nt]);
                }
            }
        } else {
            const float* hd0 = h + (size_t)dsts[rA0]*128 + quad*8;
            const float* hs0 = h + (size_t)srcs[rA0]*128 + quad*8;
            const float* hd1 = h + (size_t)dsts[rA1]*128 + quad*8;
            const float* hs1 = h + (size_t)srcs[rA1]*128 + quad*8;
            #pragma unroll
            for (int ks = 0; ks < 12; ks++) {
                s8b a0, a1;
                if (ks < 4)      { a0 = load8f_bf(hd0 + ks*32);     a1 = load8f_bf(hd1 + ks*32); }
                else if (ks < 8) { a0 = load8f_bf(hs0 + (ks-4)*32); a1 = load8f_bf(hs1 + (ks-4)*32); }
                else             { a0 = *(const s8b*)(sA0 + (ks-8)*32); a1 = *(const s8b*)(sA1 + (ks-8)*32); }
                #pragma unroll
                for (int nt = 0; nt < 8; nt++) {
                    s8b b = *(const s8b*)(Bp + nt*(16*384) + ks*32);
                    acc1[0][nt] = MFMA16(a0, b, acc1[0][nt]);
                    acc1[1][nt] = MFMA16(a1, b, acc1[1][nt]);
                }
            }
        }
    }
    LDS_FENCE();
    #pragma unroll
    for (int nt = 0; nt < 8; nt++) {
        const int col = nt*16 + c15;
        const float bias = bm1f[col];
        #pragma unroll
        for (int tl = 0; tl < 2; tl++)
            #pragma unroll
            for (int r = 0; r < 4; r++)
                ssh[(wb + tl*16 + quad*4 + r)*136 + col] = f2bs_fast(silu_f(acc1[tl][nt][r] + bias));
    }
    LDS_FENCE();

    // Layer 2: act1 @ Wm2 -> msg (LDS only)
    f32x4 acc2[2][8];
    #pragma unroll
    for (int nt = 0; nt < 8; nt++) { acc2[0][nt] = z4; acc2[1][nt] = z4; }
    {
        const short* Bp = Wm2T + (size_t)c15*128 + quad*8;
        #pragma unroll
        for (int ks = 0; ks < 4; ks++) {
            s8b a0 = *(const s8b*)(sA0 + ks*32);
            s8b a1 = *(const s8b*)(sA1 + ks*32);
            #pragma unroll
            for (int nt = 0; nt < 8; nt++) {
                s8b b = *(const s8b*)(Bp + nt*(16*128) + ks*32);
                acc2[0][nt] = MFMA16(a0, b, acc2[0][nt]);
                acc2[1][nt] = MFMA16(a1, b, acc2[1][nt]);
            }
        }
    }
    LDS_FENCE();
    #pragma unroll
    for (int nt = 0; nt < 8; nt++) {
        const int col = nt*16 + c15;
        const float bias = bm2[col];
        #pragma unroll
        for (int tl = 0; tl < 2; tl++)
            #pragma unroll
            for (int r = 0; r < 4; r++) {
                const int rw = wb + tl*16 + quad*4 + r;
                ssh[rw*136 + col] = f2bs_fast(silu_f(acc2[tl][nt][r] + bias));
            }
    }
    LDS_FENCE();

    // ---- macc segmented reduction, wave-private (own 32 sorted rows) ----
    {
        #pragma unroll
        for (int half = 0; half < 2; half++) {
            const int col = lane + half*64;
            float run = 0.f;
            int cur = dsts[wb];
            for (int r2 = wb; r2 < wb + EPW; r2++) {
                int d2 = dsts[r2];
                if (d2 != cur) {
                    atomicAdd(macc + (size_t)cur*128 + col, run);
                    run = 0.f; cur = d2;
                }
                run += bs2f(ssh[r2*136 + col]);
            }
            atomicAdd(macc + (size_t)cur*128 + col, run);
        }
    }

    // Layer 3: msg @ Wv1 -> act3
    f32x4 acc3[2][8];
    #pragma unroll
    for (int nt = 0; nt < 8; nt++) { acc3[0][nt] = z4; acc3[1][nt] = z4; }
    {
        const short* Bp = Wv1T + (size_t)c15*128 + quad*8;
        #pragma unroll
        for (int ks = 0; ks < 4; ks++) {
            s8b a0 = *(const s8b*)(sA0 + ks*32);
            s8b a1 = *(const s8b*)(sA1 + ks*32);
            #pragma unroll
            for (int nt = 0; nt < 8; nt++) {
                s8b b = *(const s8b*)(Bp + nt*(16*128) + ks*32);
                acc3[0][nt] = MFMA16(a0, b, acc3[0][nt]);
                acc3[1][nt] = MFMA16(a1, b, acc3[1][nt]);
            }
        }
    }
    LDS_FENCE();
    #pragma unroll
    for (int nt = 0; nt < 8; nt++) {
        const int col = nt*16 + c15;
        const float bias = bv1[col];
        #pragma unroll
        for (int tl = 0; tl < 2; tl++)
            #pragma unroll
            for (int r = 0; r < 4; r++)
                ssh[(wb + tl*16 + quad*4 + r)*136 + col] = f2bs_fast(silu_f(acc3[tl][nt][r] + bias));
    }
    LDS_FENCE();

    // Layer 4: act3 @ Wv2 -> basis[80]
    f32x4 acc4[2][5];
    #pragma unroll
    for (int nt = 0; nt < 5; nt++) { acc4[0][nt] = z4; acc4[1][nt] = z4; }
    {
        const short* Bp = Wv2T + (size_t)c15*128 + quad*8;
        #pragma unroll
        for (int ks = 0; ks < 4; ks++) {
            s8b a0 = *(const s8b*)(sA0 + ks*32);
            s8b a1 = *(const s8b*)(sA1 + ks*32);
            #pragma unroll
            for (int nt = 0; nt < 5; nt++) {
                s8b b = *(const s8b*)(Bp + nt*(16*128) + ks*32);
                acc4[0][nt] = MFMA16(a0, b, acc4[0][nt]);
                acc4[1][nt] = MFMA16(a1, b, acc4[1][nt]);
            }
        }
    }
    // act3 dead -> restage Z_ij from registers into ssh cols 0..59 (own rows)
    LDS_FENCE();
    {
        #pragma unroll
        for (int d2 = 0; d2 < 3; d2++) {
            #pragma unroll
            for (int t = 0; t < 4; t++)
                *(unsigned*)(&ssh[row*136 + d2*20 + t*4 + 2*sub]) = zp[d2*4 + t];
            *(unsigned*)(&ssh[row*136 + d2*20 + 16 + 2*sub]) = zp[12 + d2];
        }
    }
    LDS_FENCE();
    // contract with Z_ij ; stage Zagg (bf16) into ssh cols 64..111 (own rows)
    {
        const int hh = c15 & 3;                   // basis col = t*16 + (k*4+h); c15 = k*4+h
        float bs[5];
        #pragma unroll
        for (int t = 0; t < 5; t++) bs[t] = bv2[t*16 + c15];
        #pragma unroll
        for (int tl = 0; tl < 2; tl++)
            #pragma unroll
            for (int r = 0; r < 4; r++) {
                const int rw = wb + tl*16 + quad*4 + r;
                float bt[5];
                #pragma unroll
                for (int t = 0; t < 5; t++) bt[t] = acc4[tl][t][r] + bs[t];
                #pragma unroll
                for (int dd = 0; dd < 3; dd++) {
                    float s0 = 0.f;
                    #pragma unroll
                    for (int t = 0; t < 5; t++)
                        s0 += bs2f(ssh[rw*136 + dd*20 + t*4 + hh]) * bt[t];
                    ssh[rw*136 + 64 + dd*16 + c15] = f2bs_fast(s0);
                }
            }
    }
    LDS_FENCE();

    // ---- Zacc segmented reduction, wave-private (own 32 rows, 48 cols) ----
    {
        const int colz = lane;
        if (colz < 48) {
            float run = 0.f;
            int cur = dsts[wb];
            for (int r2 = wb; r2 < wb + EPW; r2++) {
                int d2 = dsts[r2];
                if (d2 != cur) {
                    atomicAdd(Zacc + (size_t)cur*48 + colz, run);
                    run = 0.f; cur = d2;
                }
                run += bs2f(ssh[r2*136 + 64 + colz]);
            }
            atomicAdd(Zacc + (size_t)cur*48 + colz, run);
        }
    }
}

// ---------------- node kernel ----------------
__global__ __launch_bounds__(256) void node_kernel(
    const float* __restrict__ h,
    const short* __restrict__ Ws1T, const float* __restrict__ bs1,
    const short* __restrict__ Ws2T, const float* __restrict__ bs2,
    const float* __restrict__ Zacc, const float* __restrict__ macc,
    const int* __restrict__ deg, float* __restrict__ out)
{
    __shared__ __align__(16) short ssh[64*136];   // m stage -> act1
    const int tid = threadIdx.x, lane = tid & 63, wave = tid >> 6;
    const int mb = wave*16;
    const int nbase = blockIdx.x * 64;

    // Z_out = Zacc / max(deg,1)
    for (int i = tid; i < 64*48; i += 256) {
        int nl = i / 48, c2 = i - nl*48;
        int nd = nbase + nl;
        if (nd < NND) {
            float ct = fmaxf((float)deg[nd], 1.0f);
            out[(size_t)nd*48 + c2] = Zacc[(size_t)nd*48 + c2] / ct;
        }
    }

    // stage m (bf16), wave-private rows
    {
        const int row = mb + (lane >> 2);
        const int sub = lane & 3;
        int nd = nbase + row; if (nd >= NND) nd = 0;
        const float* mr = macc + (size_t)nd*128 + sub*32;
        #pragma unroll
        for (int j = 0; j < 8; j++) {
            f32x4 v = *(const f32x4*)(mr + j*4);
            int cb = row*136 + sub*32 + j*4;
            *(unsigned*)(&ssh[cb+0]) = pk2(v[0], v[1]);
            *(unsigned*)(&ssh[cb+2]) = pk2(v[2], v[3]);
        }
    }
    LDS_FENCE();

    const int quad = lane >> 4, c15 = lane & 15;
    const int rA = mb + c15;
    int ndA = nbase + rA; if (ndA >= NND) ndA = 0;   // clamp; stores guarded
    const float* hA = h + (size_t)ndA*128 + quad*8;
    const short* sA = ssh + rA*136 + quad*8;
    const f32x4 z4 = {0.f,0.f,0.f,0.f};

    // GEMM1: [h | m] (K=256) @ Ws1
    f32x4 acc1[8];
    #pragma unroll
    for (int nt = 0; nt < 8; nt++) acc1[nt] = z4;
    {
        const short* Bp = Ws1T + (size_t)c15*256 + quad*8;
        #pragma unroll
        for (int ks = 0; ks < 8; ks++) {
            s8b a;
            if (ks < 4) a = load8f_bf(hA + ks*32);
            else        a = *(const s8b*)(sA + (ks-4)*32);
            #pragma unroll
            for (int nt = 0; nt < 8; nt++) {
                s8b b = *(const s8b*)(Bp + nt*(16*256) + ks*32);
                acc1[nt] = MFMA16(a, b, acc1[nt]);
            }
        }
    }
    LDS_FENCE();
    #pragma unroll
    for (int nt = 0; nt < 8; nt++) {
        const int col = nt*16 + c15;
        const float bias = bs1[col];
        #pragma unroll
        for (int r = 0; r < 4; r++)
            ssh[(mb + quad*4 + r)*136 + col] = f2bs_fast(silu_f(acc1[nt][r] + bias));
    }
    LDS_FENCE();

    // GEMM2: act @ Ws2 -> h_out
    f32x4 acc2[8];
    #pragma unroll
    for (int nt = 0; nt < 8; nt++) acc2[nt] = z4;
    {
        const short* Bp = Ws2T + (size_t)c15*128 + quad*8;
        #pragma unroll
        for (int ks = 0; ks < 4; ks++) {
            s8b a = *(const s8b*)(sA + ks*32);
            #pragma unroll
            for (int nt = 0; nt < 8; nt++) {
                s8b b = *(const s8b*)(Bp + nt*(16*128) + ks*32);
                acc2[nt] = MFMA16(a, b, acc2[nt]);
            }
        }
    }
    {
        float* oh = out + (size_t)NND*48;
        #pragma unroll
        for (int nt = 0; nt < 8; nt++) {
            const int col = nt*16 + c15;
            const float bias = bs2[col];
            #pragma unroll
            for (int r = 0; r < 4; r++) {
                const int rw = mb + quad*4 + r;
                const int nd = nbase + rw;
                if (nd < NND)
                    oh[(size_t)nd*128 + col] = acc2[nt][r] + bias;
            }
        }
    }
}

extern "C" void kernel_launch(void* const* d_in, const int* in_sizes, int n_in,
                              void* d_out, int out_size, void* d_ws, size_t ws_size,
                              hipStream_t stream)
{
    const float* Z   = (const float*)d_in[0];
    const float* h   = (const float*)d_in[1];
    const int*   ei  = (const int*)d_in[2];
    const float* edf = (const float*)d_in[3];
    const float* edv = (const float*)d_in[4];
    const float* We  = (const float*)d_in[6];
    const float* be  = (const float*)d_in[7];
    const float* Wm1 = (const float*)d_in[8];
    const float* bm1 = (const float*)d_in[9];
    const float* Wm2 = (const float*)d_in[10];
    const float* bm2 = (const float*)d_in[11];
    const float* Wv1 = (const float*)d_in[12];
    const float* bv1 = (const float*)d_in[13];
    const float* Wv2 = (const float*)d_in[14];
    const float* bv2 = (const float*)d_in[15];
    const float* Ws1 = (const float*)d_in[16];
    const float* bs1 = (const float*)d_in[17];
    const float* Ws2 = (const float*)d_in[18];
    const float* bs2 = (const float*)d_in[19];

    if (ws_size < WS_MIN) return;
    const bool bf = (ws_size >= WS_FULL);

    char* wsc = (char*)d_ws;
    short* wsb = (short*)d_ws;
    float* bm1f = (float*)(wsc + BM1F_BYTE);
    float* Zacc = (float*)(wsc + ACC_BYTE);
    float* macc = Zacc + ZACC_ELEMS;
    int*   deg  = (int*)(macc + MACC_ELEMS);
    int*   cursor = deg + NND;
    int*   perm   = cursor + NND;
    int*   part   = perm + NED;
    short* hbf    = (short*)(wsc + HB_BYTE);
    short* zbf    = (short*)(wsc + ZB_BYTE);

    zero_kernel<<<2048, 256, 0, stream>>>(Zacc, ACC_TOTAL);   // Zacc + macc + deg
    fold_kernel<<<192, 256, 0, stream>>>(We, be, Wm1, bm1, wsb + WM1T_OFF, bm1f);
    prep_kernel<<<360, 256, 0, stream>>>(Wm2, Wv1, Wv2, Ws1, Ws2, wsb);
    if (bf) {
        cvt_kernel<<<2048, 256, 0, stream>>>(h, hbf, NND*128);
        cvt_kernel<<<1024, 256, 0, stream>>>(Z, zbf, NND*48);
    }
    hist_kernel<<<(NED + 255)/256, 256, 0, stream>>>(ei, deg);
    scan1_kernel<<<SCH, 256, 0, stream>>>(deg, part);
    scan2_kernel<<<1, 64, 0, stream>>>(part);
    scan3_kernel<<<SCH, 256, 0, stream>>>(deg, part, cursor);
    scatter_kernel<<<(NED + 255)/256, 256, 0, stream>>>(ei, cursor, perm);
    if (bf) {
        edge_kernel<1><<<NED/EPB, 256, 0, stream>>>(Z, h, zbf, hbf, ei, perm, edf, edv,
            wsb + WM1T_OFF, bm1f, wsb + WM2T_OFF, bm2, wsb + WV1T_OFF, bv1,
            wsb + WV2T_OFF, bv2, Zacc, macc);
    } else {
        edge_kernel<0><<<NED/EPB, 256, 0, stream>>>(Z, h, zbf, hbf, ei, perm, edf, edv,
            wsb + WM1T_OFF, bm1f, wsb + WM2T_OFF, bm2, wsb + WV1T_OFF, bv1,
            wsb + WV2T_OFF, bv2, Zacc, macc);
    }
    node_kernel<<<(NND + 63)/64, 256, 0, stream>>>(h, wsb + WS1T_OFF, bs1,
        wsb + WS2T_OFF, bs2, Zacc, macc, deg, (float*)d_out);
}